// Round 1
// baseline (205.872 us; speedup 1.0000x reference)
//
#include <hip/hip_runtime.h>
#include <math.h>

#define EPS_COS 1e-8f
#define EPS_ADD 1e-12f

constexpr int NN = 4096;   // N
constexpr int MM = 64;     // M
constexpr int BLOCK = 256;

__device__ __forceinline__ float block_reduce_max(float v, float* red) {
    #pragma unroll
    for (int o = 32; o > 0; o >>= 1) v = fmaxf(v, __shfl_xor(v, o, 64));
    const int wv = threadIdx.x >> 6;
    if ((threadIdx.x & 63) == 0) red[wv] = v;
    __syncthreads();
    float r = fmaxf(fmaxf(red[0], red[1]), fmaxf(red[2], red[3]));
    __syncthreads();
    return r;
}

__device__ __forceinline__ float block_reduce_sum(float v, float* red) {
    #pragma unroll
    for (int o = 32; o > 0; o >>= 1) v += __shfl_xor(v, o, 64);
    const int wv = threadIdx.x >> 6;
    if ((threadIdx.x & 63) == 0) red[wv] = v;
    __syncthreads();
    float r = (red[0] + red[1]) + (red[2] + red[3]);
    __syncthreads();
    return r;
}

__global__ __launch_bounds__(BLOCK, 4) void ntm_fused(
    const float* __restrict__ beta,
    const float* __restrict__ kappa,
    const float* __restrict__ gamma_p,
    const float* __restrict__ g_p,
    const float* __restrict__ s_p,
    const float* __restrict__ w_prev,
    const float* __restrict__ memory,
    float* __restrict__ out,
    int S)
{
    const int b   = blockIdx.x;
    const int tid = threadIdx.x;
    const int sub = tid & 3;   // 4 threads per row, 16 floats each
    const int row = tid >> 2;  // 64 rows per sweep

    __shared__ float sc[NN];   // scores -> exp -> w_g
    __shared__ float red[4];

    const float beta_b  = beta[b];
    const float g_b     = g_p[b];
    const float gamma_b = gamma_p[b];
    float sreg[8];
    #pragma unroll
    for (int j = 0; j < 8; ++j) sreg[j] = (j < S) ? s_p[(size_t)b * S + j] : 0.0f;

    // kappa fragment: 16 floats at element sub*16 (+eps), and k-norm
    const float4* kv = (const float4*)(kappa + (size_t)b * MM);
    float4 kf[4];
    float ksq = 0.f;
    #pragma unroll
    for (int j = 0; j < 4; ++j) {
        float4 t = kv[sub * 4 + j];
        t.x += EPS_ADD; t.y += EPS_ADD; t.z += EPS_ADD; t.w += EPS_ADD;
        kf[j] = t;
        ksq += t.x * t.x + t.y * t.y + t.z * t.z + t.w * t.w;
    }
    ksq += __shfl_xor(ksq, 1, 64);
    ksq += __shfl_xor(ksq, 2, 64);
    const float knorm = fmaxf(sqrtf(ksq), EPS_COS);
    const float binv  = beta_b / knorm;

    // ---- phase 1: cosine scores into LDS ----
    const float4* memv = (const float4*)(memory + (size_t)b * NN * MM);
    #pragma unroll 2
    for (int it = 0; it < NN / 64; ++it) {
        const int n = it * 64 + row;
        const float4* rp = memv + (size_t)n * (MM / 4) + sub * 4;
        float d = 0.f, q = 0.f;
        #pragma unroll
        for (int j = 0; j < 4; ++j) {
            float4 m = rp[j];
            m.x += EPS_ADD; m.y += EPS_ADD; m.z += EPS_ADD; m.w += EPS_ADD;
            d += m.x * kf[j].x + m.y * kf[j].y + m.z * kf[j].z + m.w * kf[j].w;
            q += m.x * m.x + m.y * m.y + m.z * m.z + m.w * m.w;
        }
        d += __shfl_xor(d, 1, 64); q += __shfl_xor(q, 1, 64);
        d += __shfl_xor(d, 2, 64); q += __shfl_xor(q, 2, 64);
        if (sub == 0) {
            sc[n] = binv * d / fmaxf(sqrtf(q), EPS_COS);
        }
    }
    __syncthreads();

    // ---- phase 2: softmax over N ----
    float lmax = -INFINITY;
    #pragma unroll
    for (int k = 0; k < NN / BLOCK; ++k) lmax = fmaxf(lmax, sc[tid + k * BLOCK]);
    const float mx = block_reduce_max(lmax, red);

    float lsum = 0.f;
    #pragma unroll
    for (int k = 0; k < NN / BLOCK; ++k) {
        const float e = expf(sc[tid + k * BLOCK] - mx);
        sc[tid + k * BLOCK] = e;
        lsum += e;
    }
    const float Z  = block_reduce_sum(lsum, red);   // barrier inside orders sc writes
    const float gi = g_b / Z;
    const float gp = 1.0f - g_b;

    // ---- phase 3: interpolate with w_prev (float4) ----
    const float4* wp4 = (const float4*)(w_prev + (size_t)b * NN);
    float4* sc4 = (float4*)sc;
    #pragma unroll
    for (int k = 0; k < NN / (BLOCK * 4); ++k) {
        const int idx = tid + k * BLOCK;
        float4 e = sc4[idx];
        const float4 w = wp4[idx];
        e.x = e.x * gi + gp * w.x;
        e.y = e.y * gi + gp * w.y;
        e.z = e.z * gi + gp * w.z;
        e.w = e.w * gi + gp * w.w;
        sc4[idx] = e;
    }
    __syncthreads();

    // ---- phase 4: circular conv + sharpen + normalize ----
    float vals[NN / BLOCK];
    float lsum2 = 0.f;
    #pragma unroll
    for (int k = 0; k < NN / BLOCK; ++k) {
        const int n = tid + k * BLOCK;
        float acc = 0.f;
        for (int j = 0; j < S; ++j) {
            const int idx = (n + j - 1 + NN) & (NN - 1);
            acc += sreg[j] * sc[idx];
        }
        const float v = powf(acc, gamma_b);
        vals[k] = v;
        lsum2 += v;
    }
    const float T   = block_reduce_sum(lsum2, red);
    const float inv = 1.0f / (T + EPS_ADD);
    float* outb = out + (size_t)b * NN;
    #pragma unroll
    for (int k = 0; k < NN / BLOCK; ++k) {
        outb[tid + k * BLOCK] = vals[k] * inv;
    }
}

extern "C" void kernel_launch(void* const* d_in, const int* in_sizes, int n_in,
                              void* d_out, int out_size, void* d_ws, size_t ws_size,
                              hipStream_t stream) {
    const float* beta    = (const float*)d_in[0];
    const float* kappa   = (const float*)d_in[1];
    const float* gamma_p = (const float*)d_in[2];
    const float* g_p     = (const float*)d_in[3];
    const float* s_p     = (const float*)d_in[4];
    const float* w_prev  = (const float*)d_in[5];
    const float* memory  = (const float*)d_in[6];
    float* out = (float*)d_out;

    const int B = in_sizes[0];              // beta is (B,1)
    int S = in_sizes[4] / B;                // s is (B, INT_SHIFT)
    if (S > 8) S = 8;

    ntm_fused<<<B, BLOCK, 0, stream>>>(beta, kappa, gamma_p, g_p, s_p,
                                       w_prev, memory, out, S);
}

// Round 2
// 197.106 us; speedup vs baseline: 1.0445x; 1.0445x over previous
//
#include <hip/hip_runtime.h>
#include <math.h>

#define EPS_COS 1e-8f
#define EPS_ADD 1e-12f

constexpr int NN = 4096;   // N
constexpr int MM = 64;     // M
constexpr int BLOCK = 256;

__device__ __forceinline__ float block_reduce_sum(float v, float* red) {
    #pragma unroll
    for (int o = 32; o > 0; o >>= 1) v += __shfl_xor(v, o, 64);
    const int wv = threadIdx.x >> 6;
    if ((threadIdx.x & 63) == 0) red[wv] = v;
    __syncthreads();
    float r = (red[0] + red[1]) + (red[2] + red[3]);
    __syncthreads();
    return r;
}

__global__ __launch_bounds__(BLOCK, 4) void ntm_fused(
    const float* __restrict__ beta,
    const float* __restrict__ kappa,
    const float* __restrict__ gamma_p,
    const float* __restrict__ g_p,
    const float* __restrict__ s_p,
    const float* __restrict__ w_prev,
    const float* __restrict__ memory,
    float* __restrict__ out,
    int S)
{
    const int b   = blockIdx.x;
    const int tid = threadIdx.x;
    const int sub = tid & 3;   // 4 threads per row, 16 floats each
    const int row = tid >> 2;  // 64 rows per sweep

    __shared__ float sc[NN];   // exp(beta*cos) -> w_g
    __shared__ float red[4];

    const float beta_b  = beta[b];
    const float g_b     = g_p[b];
    const float gamma_b = gamma_p[b];
    float sreg[8];
    #pragma unroll
    for (int j = 0; j < 8; ++j) sreg[j] = (j < S) ? s_p[(size_t)b * S + j] : 0.0f;

    // kappa fragment: 16 floats at element sub*16 (+eps), and k-norm
    const float4* kv = (const float4*)(kappa + (size_t)b * MM);
    float4 kf[4];
    float ksq = 0.f;
    #pragma unroll
    for (int j = 0; j < 4; ++j) {
        float4 t = kv[sub * 4 + j];
        t.x += EPS_ADD; t.y += EPS_ADD; t.z += EPS_ADD; t.w += EPS_ADD;
        kf[j] = t;
        ksq += t.x * t.x + t.y * t.y + t.z * t.z + t.w * t.w;
    }
    ksq += __shfl_xor(ksq, 1, 64);
    ksq += __shfl_xor(ksq, 2, 64);
    const float knorm = fmaxf(sqrtf(ksq), EPS_COS);
    const float binv  = beta_b / knorm;

    // ---- phase 1: e = exp(beta*cos) into LDS, accumulate softmax denom.
    // scores are bounded: |beta*cos| < 1, so no max-subtraction is needed.
    float lsum = 0.f;
    const float4* memv = (const float4*)(memory + (size_t)b * NN * MM);
    #pragma unroll 2
    for (int it = 0; it < NN / 64; ++it) {
        const int n = it * 64 + row;
        const float4* rp = memv + (size_t)n * (MM / 4) + sub * 4;
        float d = 0.f, q = 0.f;
        #pragma unroll
        for (int j = 0; j < 4; ++j) {
            float4 m = rp[j];
            m.x += EPS_ADD; m.y += EPS_ADD; m.z += EPS_ADD; m.w += EPS_ADD;
            d += m.x * kf[j].x + m.y * kf[j].y + m.z * kf[j].z + m.w * kf[j].w;
            q += m.x * m.x + m.y * m.y + m.z * m.z + m.w * m.w;
        }
        d += __shfl_xor(d, 1, 64); q += __shfl_xor(q, 1, 64);
        d += __shfl_xor(d, 2, 64); q += __shfl_xor(q, 2, 64);
        if (sub == 0) {
            const float e = __expf(binv * d / fmaxf(sqrtf(q), EPS_COS));
            sc[n] = e;
            lsum += e;
        }
    }
    const float Z  = block_reduce_sum(lsum, red);  // barriers also order sc writes
    const float gi = g_b / Z;
    const float gp = 1.0f - g_b;

    // ---- phase 2: interpolate with w_prev (float4) ----
    const float4* wp4 = (const float4*)(w_prev + (size_t)b * NN);
    float4* sc4 = (float4*)sc;
    #pragma unroll
    for (int k = 0; k < NN / (BLOCK * 4); ++k) {
        const int idx = tid + k * BLOCK;
        float4 e = sc4[idx];
        const float4 w = wp4[idx];
        e.x = e.x * gi + gp * w.x;
        e.y = e.y * gi + gp * w.y;
        e.z = e.z * gi + gp * w.z;
        e.w = e.w * gi + gp * w.w;
        sc4[idx] = e;
    }
    __syncthreads();

    // ---- phase 3: circular conv + sharpen + normalize ----
    float vals[NN / BLOCK];
    float lsum2 = 0.f;
    #pragma unroll
    for (int k = 0; k < NN / BLOCK; ++k) {
        const int n = tid + k * BLOCK;
        float acc = 0.f;
        for (int j = 0; j < S; ++j) {
            const int idx = (n + j - 1 + NN) & (NN - 1);
            acc += sreg[j] * sc[idx];
        }
        // powf(acc, gamma) via hardware log2/exp2; acc==0 -> exp(-inf)=0 (exact)
        const float v = __expf(gamma_b * __logf(acc));
        vals[k] = v;
        lsum2 += v;
    }
    const float T   = block_reduce_sum(lsum2, red);
    const float inv = 1.0f / (T + EPS_ADD);
    float* outb = out + (size_t)b * NN;
    #pragma unroll
    for (int k = 0; k < NN / BLOCK; ++k) {
        outb[tid + k * BLOCK] = vals[k] * inv;
    }
}

extern "C" void kernel_launch(void* const* d_in, const int* in_sizes, int n_in,
                              void* d_out, int out_size, void* d_ws, size_t ws_size,
                              hipStream_t stream) {
    const float* beta    = (const float*)d_in[0];
    const float* kappa   = (const float*)d_in[1];
    const float* gamma_p = (const float*)d_in[2];
    const float* g_p     = (const float*)d_in[3];
    const float* s_p     = (const float*)d_in[4];
    const float* w_prev  = (const float*)d_in[5];
    const float* memory  = (const float*)d_in[6];
    float* out = (float*)d_out;

    const int B = in_sizes[0];              // beta is (B,1)
    int S = in_sizes[4] / B;                // s is (B, INT_SHIFT)
    if (S > 8) S = 8;

    ntm_fused<<<B, BLOCK, 0, stream>>>(beta, kappa, gamma_p, g_p, s_p,
                                       w_prev, memory, out, S);
}